// Round 8
// baseline (5241.278 us; speedup 1.0000x reference)
//
#include <hip/hip_runtime.h>
#include <cstdint>
#include <cstddef>

#define B_   64
#define T_   512
#define E_   512
#define H_   1024
#define G4_  4096
#define KTOT 1536
#define NWG  256

typedef float f32x4 __attribute__((ext_vector_type(4)));
typedef int   i32x4 __attribute__((ext_vector_type(4)));

#define OFF_XE    ((size_t)0)
#define OFF_WC    (OFF_XE + (size_t)T_*B_*E_*2)     // 32 MB
#define OFF_BIAS  (OFF_WC + (size_t)G4_*KTOT*2)     // +12.6 MB
#define OFF_H0    (OFF_BIAS + (size_t)G4_*4)
#define OFF_HBUF  (OFF_H0 + (size_t)B_*H_*2)        // 2 x 64 x 1024 dwords

__device__ __forceinline__ unsigned short f2b(float f) {
    unsigned u = __float_as_uint(f);
    return (unsigned short)((u + 0x7fffu + ((u >> 16) & 1u)) >> 16);  // RNE
}

// Permuted combined weights: permuted row p = s*64 + q*16 + hl  <->
// original gate row q*1024 + s*16 + hl (q: i,f,g,o; s: 16-hdim block).
// Row = [W_ih | W_hh], bf16.
__global__ void prep_w(const float* __restrict__ wih, const float* __restrict__ whh,
                       const float* __restrict__ bih, const float* __restrict__ bhh,
                       unsigned short* __restrict__ Wc, float* __restrict__ bp) {
    int p = blockIdx.x;
    int s = p >> 6, q = (p >> 4) & 3, hl = p & 15;
    int orig = q * H_ + s * 16 + hl;
    unsigned short* dst = Wc + (size_t)p * KTOT;
    const float* s1 = wih + (size_t)orig * E_;
    const float* s2 = whh + (size_t)orig * H_;
    int tx = threadIdx.x;
#pragma unroll
    for (int i = 0; i < 2; ++i) dst[tx + i*256] = f2b(s1[tx + i*256]);
#pragma unroll
    for (int i = 0; i < 4; ++i) dst[E_ + tx + i*256] = f2b(s2[tx + i*256]);
    if (tx == 0) bp[p] = bih[orig] + bhh[orig];
}

// xe[t][b][0:512] = bf16(emb[x[b][t]])
__global__ void prep_xe(const int* __restrict__ x, const float* __restrict__ emb,
                        unsigned short* __restrict__ xe) {
    int bid = blockIdx.x;
    int t = bid >> 6, b = bid & 63;
    int idx = x[b * T_ + t];
    const float* src = emb + (size_t)idx * E_;
    unsigned short* dst = xe + ((size_t)t * B_ + b) * E_;
    int tx = threadIdx.x;
    dst[tx] = f2b(src[tx]);
    dst[tx + 256] = f2b(src[tx + 256]);
}

__global__ void prep_h(const float* __restrict__ h0, unsigned short* __restrict__ hb) {
    int b = blockIdx.x;
#pragma unroll
    for (int i = 0; i < 4; ++i) {
        int j = threadIdx.x + i*256;
        hb[(size_t)b * H_ + j] = f2b(h0[(size_t)b * H_ + j]);
    }
}

// Persistent kernel, plain launch, NO grid barrier. 256 WGs = 4 independent
// groups (g = blockIdx&3 owns batch rows [16g,16g+16); s = blockIdx>>2 ->
// 64 gate-cols). 256 threads = 4 waves (ch = col half, kh = K half).
// h travels as TAGGED dwords ((t+1)<<16 | bf16(h)) through a ping-pong hbuf
// at the coherent point (bypass stores). Consumers bypass-load and retry
// until every dword's tag == t: the data certifies its own readiness, so
// there is no drain, no counter, no poll. Ping-pong safe by dataflow order.
__global__ __launch_bounds__(256, 1)
void lstm_pers(const unsigned short* __restrict__ xe,
               const unsigned short* __restrict__ Wc,
               const float* __restrict__ bp,
               const float* __restrict__ c0,
               const unsigned short* __restrict__ hb0,
               float* __restrict__ out,
               unsigned* __restrict__ hbuf) {
    __shared__ float gpart[2][16][68];

    const int tid = threadIdx.x;
    const int wg  = blockIdx.x;
    const int g   = wg & 3;              // batch group: rows [16g, 16g+16)
    const int s   = wg >> 2;             // gate block: permuted cols [64s, 64s+64)
    const int w = tid >> 6, l = tid & 63;
    const int ch = w >> 1, kh = w & 1;
    const int lc = l & 15;               // lane col (B) / row (A)
    const int lk = (l >> 4) << 3;        // lane k-offset (elements)

    // ---- W fragments (AGPRs via "a" asm constraints): frag j<8 = xe part,
    //      frag 8+j = h part ----
    i32x4 wreg0[24], wreg1[24];
    {
        const unsigned short* wrow0 = Wc + (size_t)((s << 6) + (ch << 5) + lc) * KTOT;
        const unsigned short* wrow1 = wrow0 + (size_t)16 * KTOT;
#pragma unroll
        for (int j = 0; j < 8; ++j) {
            int k = (kh << 8) + j * 32 + lk;
            wreg0[j] = *(const i32x4*)(wrow0 + k);
            wreg1[j] = *(const i32x4*)(wrow1 + k);
        }
#pragma unroll
        for (int j = 0; j < 16; ++j) {
            int k = 512 + (kh << 9) + j * 32 + lk;
            wreg0[8 + j] = *(const i32x4*)(wrow0 + k);
            wreg1[8 + j] = *(const i32x4*)(wrow1 + k);
        }
    }

    const int brow = (g << 4) + lc;      // global batch row this lane loads

    // ---- cell ownership: thread (b_c, hl_c); c stays in a register all T ----
    const int b_c = tid >> 4, hl_c = tid & 15;
    const int bglob = (g << 4) + b_c;
    const int hdim = (s << 4) + hl_c;
    float c = c0[(size_t)bglob * H_ + hdim];
    const float bi  = bp[(s << 6) + hl_c];
    const float bf_ = bp[(s << 6) + 16 + hl_c];
    const float bg  = bp[(s << 6) + 32 + hl_c];
    const float bo  = bp[(s << 6) + 48 + hl_c];

    for (int t = 0; t < T_; ++t) {
        // ---- xe frags (cached; L2/L3-resident) ----
        i32x4 a[24];
        {
            const unsigned short* xp = xe + ((size_t)t * B_ + brow) * E_ + (kh << 8) + lk;
#pragma unroll
            for (int j = 0; j < 8; ++j) a[j] = *(const i32x4*)(xp + j * 32);
        }

        int dead = 0;
        if (t == 0) {
            const unsigned short* hp = hb0 + (size_t)brow * H_ + (kh << 9) + lk;
#pragma unroll
            for (int j = 0; j < 16; ++j) a[8 + j] = *(const i32x4*)(hp + j * 32);
        } else {
            // ---- tagged h(t-1) from ping-pong hbuf: bypass-load + retry ----
            const unsigned* hb = hbuf + (((t & 1) ^ 1) << 16)
                                      + ((unsigned)brow << 10) + (kh << 9) + lk;
            const unsigned tgt = (unsigned)t << 16;
            i32x4 raw[16][2];
            unsigned spin = 0;
            for (;;) {
#pragma unroll
                for (int j = 0; j < 16; ++j) {
                    asm volatile("global_load_dwordx4 %0, %1, off offset:%2 sc0 sc1"
                                 : "=v"(raw[j][0]) : "v"(hb), "i"(j * 128));
                    asm volatile("global_load_dwordx4 %0, %1, off offset:%2 sc0 sc1"
                                 : "=v"(raw[j][1]) : "v"(hb), "i"(j * 128 + 16));
                }
                asm volatile("s_waitcnt vmcnt(0)" ::: "memory");
                unsigned bad = 0;
#pragma unroll
                for (int j = 0; j < 16; ++j)
#pragma unroll
                    for (int q = 0; q < 2; ++q) {
                        bad |= ((unsigned)raw[j][q][0] ^ tgt);
                        bad |= ((unsigned)raw[j][q][1] ^ tgt);
                        bad |= ((unsigned)raw[j][q][2] ^ tgt);
                        bad |= ((unsigned)raw[j][q][3] ^ tgt);
                    }
                bad &= 0xFFFF0000u;                  // only tag bits
                if (__all(bad == 0)) break;          // wave-uniform
                if (++spin > 512) { dead = 1; break; }  // escape, no hang
            }
            // ---- pack tagged dwords -> bf16x8 A-frags ----
#pragma unroll
            for (int j = 0; j < 16; ++j) {
                i32x4 pk;
                pk[0] = (raw[j][0][0] & 0xFFFF) | (raw[j][0][1] << 16);
                pk[1] = (raw[j][0][2] & 0xFFFF) | (raw[j][0][3] << 16);
                pk[2] = (raw[j][1][0] & 0xFFFF) | (raw[j][1][1] << 16);
                pk[3] = (raw[j][1][2] & 0xFFFF) | (raw[j][1][3] << 16);
                a[8 + j] = pk;
            }
        }
        if (__syncthreads_or(dead)) break;   // also orders vs gpart reuse

        f32x4 acc0 = {0.f, 0.f, 0.f, 0.f};
        f32x4 acc1 = {0.f, 0.f, 0.f, 0.f};
        // s_nop prefixes cover VALU(pack/init) -> MFMA SrcA/SrcC hazards.
        asm volatile("s_nop 3\n\tv_mfma_f32_16x16x32_bf16 %0, %1, %2, %0"
                     : "+v"(acc0) : "v"(a[0]), "a"(wreg0[0]));
        asm volatile("s_nop 3\n\tv_mfma_f32_16x16x32_bf16 %0, %1, %2, %0"
                     : "+v"(acc1) : "v"(a[0]), "a"(wreg1[0]));
#pragma unroll
        for (int j = 1; j < 24; ++j) {
            asm volatile("s_nop 1\n\tv_mfma_f32_16x16x32_bf16 %0, %1, %2, %0"
                         : "+v"(acc0) : "v"(a[j]), "a"(wreg0[j]));
            asm volatile("s_nop 1\n\tv_mfma_f32_16x16x32_bf16 %0, %1, %2, %0"
                         : "+v"(acc1) : "v"(a[j]), "a"(wreg1[j]));
        }
        asm volatile("s_nop 7\n\ts_nop 7\n\ts_nop 7"
                     : "+v"(acc0), "+v"(acc1) :: "memory");  // MFMA -> read D
        {
            const int grow = (l >> 4) << 2;
            const int cb = (ch << 5) + lc;
#pragma unroll
            for (int j = 0; j < 4; ++j) {
                gpart[kh][grow + j][cb]      = acc0[j];
                gpart[kh][grow + j][cb + 16] = acc1[j];
            }
        }
        __syncthreads();

        // ---- LSTM cell (one (b,hdim) per thread) ----
        {
            float xi = gpart[0][b_c][hl_c]      + gpart[1][b_c][hl_c]      + bi;
            float xf = gpart[0][b_c][16 + hl_c] + gpart[1][b_c][16 + hl_c] + bf_;
            float xg = gpart[0][b_c][32 + hl_c] + gpart[1][b_c][32 + hl_c] + bg;
            float xo = gpart[0][b_c][48 + hl_c] + gpart[1][b_c][48 + hl_c] + bo;
            float iv = 1.f / (1.f + __expf(-xi));
            float fv = 1.f / (1.f + __expf(-xf));
            float eg = __expf(2.f * fminf(fmaxf(xg, -15.f), 15.f));
            float gv = (eg - 1.f) / (eg + 1.f);
            float ov = 1.f / (1.f + __expf(-xo));
            c = fv * c + iv * gv;
            float ec = __expf(2.f * fminf(fmaxf(c, -15.f), 15.f));
            float th = (ec - 1.f) / (ec + 1.f);
            float hv = ov * th;
            // final output: plain nontemporal (flushed at kernel end)
            __builtin_nontemporal_store(hv, &out[((size_t)bglob * T_ + t) * H_ + hdim]);
            // tagged h broadcast: bypass store to coherent point; next load
            // phase's vmcnt(0) drains it for free.
            unsigned dw = ((unsigned)(t + 1) << 16) | (unsigned)f2b(hv);
            __hip_atomic_store(&hbuf[((unsigned)(t & 1) << 16) + (bglob << 10) + hdim],
                               dw, __ATOMIC_RELAXED, __HIP_MEMORY_SCOPE_AGENT);
        }
    }
}

extern "C" void kernel_launch(void* const* d_in, const int* in_sizes, int n_in,
                              void* d_out, int out_size, void* d_ws, size_t ws_size,
                              hipStream_t stream) {
    const int*   x   = (const int*)  d_in[0];
    const float* emb = (const float*)d_in[1];
    const float* wih = (const float*)d_in[2];
    const float* whh = (const float*)d_in[3];
    const float* bih = (const float*)d_in[4];
    const float* bhh = (const float*)d_in[5];
    const float* h0  = (const float*)d_in[6];
    const float* c0  = (const float*)d_in[7];
    float* out = (float*)d_out;
    char* ws = (char*)d_ws;

    unsigned short* xe  = (unsigned short*)(ws + OFF_XE);
    unsigned short* Wc  = (unsigned short*)(ws + OFF_WC);
    float*          bp  = (float*)(ws + OFF_BIAS);
    unsigned short* hb0 = (unsigned short*)(ws + OFF_H0);
    unsigned*       hbf = (unsigned*)(ws + OFF_HBUF);

    (void)hipMemsetAsync(hbf, 0, (size_t)2 * B_ * H_ * 4, stream);  // tag 0 != any
    prep_w <<<dim3(G4_),   dim3(256), 0, stream>>>(wih, whh, bih, bhh, Wc, bp);
    prep_xe<<<dim3(B_*T_), dim3(256), 0, stream>>>(x, emb, xe);
    prep_h <<<dim3(B_),    dim3(256), 0, stream>>>(h0, hb0);

    lstm_pers<<<dim3(NWG), dim3(256), 0, stream>>>(xe, Wc, bp, c0, hb0, out, hbf);
}